// Round 9
// baseline (5109.857 us; speedup 1.0000x reference)
//
#include <hip/hip_runtime.h>
#include <hip/hip_bf16.h>
#include <math.h>

typedef unsigned short ushort_t;
typedef unsigned int uint_t;

// Problem constants: S=32 scenes, N=32 peds, B=1024, E=64, H=128, PRE=512, MLP_D=1024, T=12
// All float inputs are f32; output is f32.
#define T_ 12

// ---- ws layout (float offsets) ----
#define F_LP0   0         // last_pos      (2048)
#define F_LPR   2048      // last_pos_rel  (2048)
#define F_H0    4096      // h0            (131072)
#define F_C0    135168    // c0            (131072)
#define F_WSP   266240    // Wsp (64,2)
#define F_BSP   266368    // bsp (64)
#define F_WIH   266432    // Wih (512,64)
#define F_WHH   299200    // Whh (512,128)
#define F_BIH   364736
#define F_BHH   365248
#define F_WH2P  365760    // (2,128)
#define F_BH2P  366016    // (2)
#define F_WPE   366032    // (64,2)
#define F_BPE   366160    // (64)
#define F_WP1   366224    // (512,192)
#define F_BP1   464528    // (512)
#define F_WP2   465040    // (128,512)
#define F_BP2   530576    // (128)
#define F_WM1   530704    // (1024,256)
#define F_BM1   792848    // (1024)
#define F_WM2   793872    // (128,1024)
#define F_BM2   924944    // (128)
// State / derived:
#define OFF_HC   925072   // carry hidden (B,128)
#define OFF_HL   1056144  // lstm hidden  (B,128)
#define OFF_C    1187216  // cell         (B,128)
#define OFF_X    1318288  // lstm input   (B,64)
#define OFF_LP   1383824  // positions    (B,2)
#define OFF_HP   1385872  // hp f32 (B,512)
#define OFF_A2   1910160  // (2,512)
#define OFF_B512 1911184  // (512)
#define OFF_W2F  1911696  // Wp2 bf16 B-frag pack (65536 ushorts)
#define OFF_PHP  1977232  // pool max output (B,128)
#define OFF_HPF  2108304  // Wp1b B-frag pack (65536 ushorts)
#define OFF_M1F  2141072  // Wm1 B-frag pack (262144 ushorts)
#define OFF_M2F  2272144  // Wm2 B-frag pack (131072 ushorts)
#define OFF_BG   2337680  // gate bias bih+bhh (512)
#define OFF_LF   2338192  // Wih|Whh B-frag pack (98304 ushorts = 49152 floats)
#define OFF_BAR  2387344  // grid barrier {count, generation} (2 uints)
// total ~2387346 floats = ~9.55 MB of d_ws

typedef __attribute__((ext_vector_type(8))) short short8v;   // 8 bf16 (4 VGPRs)
typedef __attribute__((ext_vector_type(4))) float f32x4;

__device__ __forceinline__ float sigf(float x){ return 1.0f/(1.0f+expf(-x)); }
__device__ __forceinline__ uint_t f2b(float f){  // RNE f32->bf16 (bits in low 16)
    uint_t u = __float_as_uint(f);
    return (u + 0x7FFFu + ((u >> 16) & 1u)) >> 16;
}

struct Ptrs { const void* p[22]; };

// ---- manual grid barrier (generation counter, agent scope; state re-zeroed each call) ----
// Co-residency by construction: grid=256 blocks, 45KB LDS, 1 block/CU on 256 CUs.
__device__ __forceinline__ void grid_barrier(uint_t* bar)
{
    __syncthreads();
    if (threadIdx.x == 0) {
        uint_t g = __hip_atomic_load(bar + 1, __ATOMIC_RELAXED, __HIP_MEMORY_SCOPE_AGENT);
        if (__hip_atomic_fetch_add(bar, 1u, __ATOMIC_ACQ_REL, __HIP_MEMORY_SCOPE_AGENT) == 255u) {
            __hip_atomic_store(bar, 0u, __ATOMIC_RELAXED, __HIP_MEMORY_SCOPE_AGENT);
            __hip_atomic_fetch_add(bar + 1, 1u, __ATOMIC_ACQ_REL, __HIP_MEMORY_SCOPE_AGENT);
        } else {
            while (__hip_atomic_load(bar + 1, __ATOMIC_ACQUIRE, __HIP_MEMORY_SCOPE_AGENT) == g)
                __builtin_amdgcn_s_sleep(2);
        }
    }
    __syncthreads();
}

// ---------------- copy all f32 inputs into consolidated ws region ----------------
__global__ __launch_bounds__(256) void k_conv(Ptrs ptrs, float* __restrict__ ws)
{
    const int cums[22] = {0,2048,4096,135168,266240,266368,266432,299200,364736,
                          365248,365760,366016,366018,366146,366210,464514,465026,
                          530562,530690,792834,793858,924930};
    const int dof[22]  = {F_LP0,F_LPR,F_H0,F_C0,F_WSP,F_BSP,F_WIH,F_WHH,F_BIH,F_BHH,
                          F_WH2P,F_BH2P,F_WPE,F_BPE,F_WP1,F_BP1,F_WP2,F_BP2,F_WM1,
                          F_BM1,F_WM2,F_BM2};
    const int TOTAL = 925058;
    int g = blockIdx.x*256 + threadIdx.x;
    if (g < TOTAL) {
        int t = 0;
        #pragma unroll
        for (int i = 1; i < 22; i++) t += (g >= cums[i]);
        int li = g - cums[t];
        ws[dof[t] + li] = ((const float*)ptrs.p[t])[li];
    }
}

// ---------------- init: h,c copy; x0 = lpr@Wsp^T+bsp; lp = last_pos; bar=0 ----------------
__global__ __launch_bounds__(128) void k_init(float* __restrict__ ws)
{
    const int b = blockIdx.x, tid = threadIdx.x;
    ws[OFF_HC + b*128 + tid] = ws[F_H0 + b*128 + tid];
    ws[OFF_C  + b*128 + tid] = ws[F_C0 + b*128 + tid];
    if (tid < 64) {
        float p0 = ws[F_LPR + b*2], p1 = ws[F_LPR + b*2 + 1];
        ws[OFF_X + b*64 + tid] = p0*ws[F_WSP + tid*2] + p1*ws[F_WSP + tid*2+1] + ws[F_BSP + tid];
    }
    if (tid < 2) ws[OFF_LP + b*2 + tid] = ws[F_LP0 + b*2 + tid];
    if (b == 0 && tid < 2) ((uint_t*)(ws + OFF_BAR))[tid] = 0u;   // barrier state each call
}

// ---------------- A2/B512 + gate bias ----------------
__global__ __launch_bounds__(256) void k_pre2(float* __restrict__ ws)
{
    const int k = blockIdx.x*256 + threadIdx.x;   // 0..511
    float a0 = 0.f, a1 = 0.f, bb = 0.f;
    for (int e = 0; e < 64; e++) {
        float w = ws[F_WP1 + k*192 + e];
        a0 += ws[F_WPE + e*2 + 0] * w;
        a1 += ws[F_WPE + e*2 + 1] * w;
        bb += ws[F_BPE + e]       * w;
    }
    ws[OFF_A2 + k]       = a0;
    ws[OFF_A2 + 512 + k] = a1;
    ws[OFF_B512 + k]     = bb + ws[F_BP1 + k];
    ws[OFF_BG + k]       = ws[F_BIH + k] + ws[F_BHH + k];
}

// ---------------- merged B-frag packs: W2F, HPF, M1F, M2F, LF ----------------
__global__ __launch_bounds__(256) void k_packs(float* __restrict__ ws)
{
    const int g = blockIdx.x*256 + threadIdx.x;
    if (g >= 622592) return;
    const int cums[6] = {0,65536,131072,393216,524288,622592};
    int rgn = 0;
    #pragma unroll
    for (int i = 1; i < 5; i++) rgn += (g >= cums[i]);
    const int li = g - cums[rgn];
    const int Ks[5]   = {512, 128, 256, 1024, 192};
    const int src[5]  = {F_WP2, F_WP1, F_WM1, F_WM2, 0};
    const int strd[5] = {512, 192, 256, 1024, 0};
    const int coff[5] = {0, 64, 0, 0, 0};
    const int dst[5]  = {OFF_W2F, OFF_HPF, OFF_M1F, OFF_M2F, OFF_LF};
    const int K = Ks[rgn];
    const int i = li & 7, lane = (li >> 3) & 63, rest = li >> 9;
    const int nkk = K >> 5, kk = rest % nkk, nt = rest / nkk;
    const int n = nt*16 + (lane & 15);
    const int k = kk*32 + ((lane >> 4) << 3) + i;
    float v;
    if (rgn == 4) v = (k < 64) ? ws[F_WIH + n*64 + k] : ws[F_WHH + n*128 + (k - 64)];
    else          v = ws[src[rgn] + n*strd[rgn] + coff[rgn] + k];
    ((ushort_t*)(ws + dst[rgn]))[li] = (ushort_t)f2b(v);
}

// ================= persistent-kernel phase functions =================

// LSTM 16 rows: gates MFMA + pointwise + h2p + X refresh + hp GEMM
__device__ void lstm_phase(float* __restrict__ ws, float* __restrict__ out,
                           char* smem, int rb, int tstep, int do_hp)
{
    ushort_t* atile = (ushort_t*)smem;              // [16*192] bf16 swz (stage)
    float*    gates = (float*)smem;                 // [16][512] f32
    float*    h2s   = (float*)(smem + 32768);       // [16][128] f32
    ushort_t* h2b   = (ushort_t*)(smem + 40960);    // [16*128] bf16 swz
    float*    relsh = (float*)(smem + 45056);       // [16][2]
    const int tid = threadIdx.x;
    float* X  = ws + OFF_X;  float* HC = ws + OFF_HC; float* C = ws + OFF_C;
    float* HL = ws + OFF_HL; float* LP = ws + OFF_LP;

    // stage A = [X(64) | HC(128)]
    for (int idx = tid; idx < 384; idx += 256) {
        const int r = idx / 24, k8 = idx - r*24, k = k8*8, gr = rb + r;
        const float* src = (k < 64) ? (X + gr*64 + k) : (HC + gr*128 + (k - 64));
        float4 f0 = ((const float4*)src)[0];
        float4 f1 = ((const float4*)src)[1];
        uint4 val;
        val.x = f2b(f0.x) | (f2b(f0.y) << 16);
        val.y = f2b(f0.z) | (f2b(f0.w) << 16);
        val.z = f2b(f1.x) | (f2b(f1.y) << 16);
        val.w = f2b(f1.z) | (f2b(f1.w) << 16);
        *(uint4*)&atile[(r*192 + k) ^ ((r & 7) << 3)] = val;
    }
    __syncthreads();

    const int lane = tid & 63, w = tid >> 6;
    const int arow = lane & 15, kch = (lane >> 4) * 8;

    short8v afr[6];
    #pragma unroll
    for (int kk = 0; kk < 6; kk++)
        afr[kk] = *(const short8v*)&atile[(arow*192 + kk*32 + kch) ^ ((arow & 7) << 3)];
    __syncthreads();   // atile free -> gates region

    const ushort_t* LF = (const ushort_t*)(ws + OFF_LF);
    #pragma unroll
    for (int ct = 0; ct < 8; ct++) {
        const int ntg = w*8 + ct;
        f32x4 acc = (f32x4){0.f,0.f,0.f,0.f};
        #pragma unroll
        for (int kk = 0; kk < 6; kk++) {
            short8v b = *(const short8v*)&LF[((ntg*6 + kk)*64 + lane)*8];
            acc = __builtin_amdgcn_mfma_f32_16x16x32_bf16(afr[kk], b, acc, 0, 0, 0);
        }
        const int col = ntg*16 + (lane & 15);
        const float bb = ws[OFF_BG + col];
        const int rb4 = (lane >> 4) << 2;
        #pragma unroll
        for (int reg = 0; reg < 4; reg++)
            gates[(rb4 + reg)*512 + col] = acc[reg] + bb;
    }
    __syncthreads();

    // pointwise
    const int hcol = tid & 127, half = tid >> 7;
    float h2v[8];
    #pragma unroll 2
    for (int rr = 0; rr < 8; rr++) {
        const int r = half*8 + rr, gr = rb + r;
        float gi = gates[r*512 + hcol];
        float gf = gates[r*512 + 128 + hcol];
        float gg = gates[r*512 + 256 + hcol];
        float go = gates[r*512 + 384 + hcol];
        float c2 = sigf(gf) * C[gr*128 + hcol] + sigf(gi) * tanhf(gg);
        float h2 = sigf(go) * tanhf(c2);
        C [gr*128 + hcol] = c2;
        HL[gr*128 + hcol] = h2;
        h2v[rr] = h2;
    }
    __syncthreads();
    #pragma unroll
    for (int rr = 0; rr < 8; rr++) {
        const int r = half*8 + rr;
        h2s[r*128 + hcol] = h2v[rr];
        h2b[(r*128 + hcol) ^ ((r & 7) << 3)] = (ushort_t)f2b(h2v[rr]);
    }
    __syncthreads();

    // h2p: rel = h2 @ Wh2p^T + bh2p  (32 dots, 8 lanes each)
    {
        const int grp = tid >> 3, sub = tid & 7;
        const int r = grp >> 1, rr = grp & 1;
        float a = 0.f;
        #pragma unroll 4
        for (int l = 0; l < 16; l++) {
            const int k = sub*16 + l;
            a += h2s[r*128 + k] * ws[F_WH2P + rr*128 + k];
        }
        a += __shfl_xor(a, 1, 64);
        a += __shfl_xor(a, 2, 64);
        a += __shfl_xor(a, 4, 64);
        if (sub == 0) {
            const float rel = a + ws[F_BH2P + rr];
            const int gr = rb + r;
            out[tstep*2048 + gr*2 + rr] = rel;
            LP[gr*2 + rr] += rel;
            relsh[r*2 + rr] = rel;
        }
    }
    __syncthreads();

    // X refresh
    {
        const int col = tid & 63, rq = tid >> 6;
        const float w0 = ws[F_WSP + col*2], w1 = ws[F_WSP + col*2 + 1], bs = ws[F_BSP + col];
        #pragma unroll
        for (int rr = 0; rr < 4; rr++) {
            const int r = rq*4 + rr;
            X[(rb + r)*64 + col] = relsh[r*2]*w0 + relsh[r*2 + 1]*w1 + bs;
        }
    }

    // hp GEMM: HP = h2 @ Wp1b^T + B512
    if (do_hp) {
        const ushort_t* HPF = (const ushort_t*)(ws + OFF_HPF);
        float* HP = ws + OFF_HP;
        short8v hf[4];
        #pragma unroll
        for (int kk = 0; kk < 4; kk++)
            hf[kk] = *(const short8v*)&h2b[(arow*128 + kk*32 + kch) ^ ((arow & 7) << 3)];
        #pragma unroll
        for (int ct = 0; ct < 8; ct++) {
            const int ntg = w*8 + ct;
            f32x4 acc = (f32x4){0.f,0.f,0.f,0.f};
            #pragma unroll
            for (int kk = 0; kk < 4; kk++) {
                short8v b = *(const short8v*)&HPF[((ntg*4 + kk)*64 + lane)*8];
                acc = __builtin_amdgcn_mfma_f32_16x16x32_bf16(hf[kk], b, acc, 0, 0, 0);
            }
            const int col = ntg*16 + (lane & 15);
            const float bb = ws[OFF_B512 + col];
            const int rb4 = (lane >> 4) << 2;
            #pragma unroll
            for (int reg = 0; reg < 4; reg++)
                HP[(rb + rb4 + reg)*512 + col] = acc[reg] + bb;
        }
    }
}

// Pool: 4 sequential (scene,i) per block
__device__ void pool_phase(float* __restrict__ ws, char* smem, int bid)
{
    uint_t* a1b = (uint_t*)smem;   // 32 KB: bf16 [j][k] swz
    const int tid = threadIdx.x;
    const int s  = bid >> 3;
    const int ig = (bid & 7) * 4;
    const float* LP = ws + OFF_LP;
    const float4* HP4 = (const float4*)(ws + OFF_HP);
    const float4* A2q = (const float4*)(ws + OFF_A2);
    const ushort_t* w2f = (const ushort_t*)(ws + OFF_W2F);
    const ushort_t* a1u = (const ushort_t*)a1b;
    const int lane = tid & 63, w = tid >> 6;
    const int r0row = (lane & 15), kchunk = (lane >> 4) * 8;

    for (int q = 0; q < 4; q++) {
        const int si = s*32 + ig + q;
        const float c0 = LP[si*2], c1 = LP[si*2 + 1];

        for (int idx = tid; idx < 32*128; idx += 256) {
            const int jl = idx >> 7, k4 = idx & 127;
            const int gj = s*32 + jl;
            const float r0 = LP[gj*2] - c0, r1 = LP[gj*2+1] - c1;
            float4 hp = HP4[gj*128 + k4];
            float4 a0 = A2q[k4];
            float4 a1v = A2q[128 + k4];
            float x = fmaxf(hp.x + r0*a0.x + r1*a1v.x, 0.f);
            float y = fmaxf(hp.y + r0*a0.y + r1*a1v.y, 0.f);
            float z = fmaxf(hp.z + r0*a0.z + r1*a1v.z, 0.f);
            float w2 = fmaxf(hp.w + r0*a0.w + r1*a1v.w, 0.f);
            const int u = (jl*512 + k4*4) ^ ((jl & 7) << 3);
            uint2 pk;
            pk.x = f2b(x) | (f2b(y) << 16);
            pk.y = f2b(z) | (f2b(w2) << 16);
            *(uint2*)&a1b[u >> 1] = pk;
        }
        __syncthreads();

        f32x4 acc[2][2];
        #pragma unroll
        for (int jt = 0; jt < 2; jt++)
            #pragma unroll
            for (int t = 0; t < 2; t++) acc[jt][t] = (f32x4){0.f,0.f,0.f,0.f};

        #pragma unroll 4
        for (int kk = 0; kk < 16; kk++) {
            const int kbase = kk*32 + kchunk;
            const int ra = r0row, rb2 = 16 + r0row;
            short8v a0 = *(const short8v*)&a1u[(ra *512 + kbase) ^ ((ra  & 7) << 3)];
            short8v a1f= *(const short8v*)&a1u[(rb2*512 + kbase) ^ ((rb2 & 7) << 3)];
            #pragma unroll
            for (int t = 0; t < 2; t++) {
                const int mt = 2*w + t;
                short8v b = *(const short8v*)&w2f[((mt*16 + kk)*64 + lane)*8];
                acc[0][t] = __builtin_amdgcn_mfma_f32_16x16x32_bf16(a0,  b, acc[0][t], 0, 0, 0);
                acc[1][t] = __builtin_amdgcn_mfma_f32_16x16x32_bf16(a1f, b, acc[1][t], 0, 0, 0);
            }
        }

        float vt[2];
        #pragma unroll
        for (int t = 0; t < 2; t++) {
            float m0 = fmaxf(fmaxf(acc[0][t][0], acc[0][t][1]), fmaxf(acc[0][t][2], acc[0][t][3]));
            float m1 = fmaxf(fmaxf(acc[1][t][0], acc[1][t][1]), fmaxf(acc[1][t][2], acc[1][t][3]));
            float m = fmaxf(m0, m1);
            m = fmaxf(m, __shfl_xor(m, 16, 64));
            m = fmaxf(m, __shfl_xor(m, 32, 64));
            const int col = (2*w + t)*16 + (lane & 15);
            vt[t] = fmaxf(m + ws[F_BP2 + col], 0.f);
        }
        if (lane < 32) {
            const int tl = lane >> 4;
            const int col = (2*w + tl)*16 + (lane & 15);
            ws[OFF_PHP + si*128 + col] = tl ? vt[1] : vt[0];
        }
        __syncthreads();
    }
}

// Fused MLP 16 rows: HC = relu(relu([HL|PHP]@Wm1^T+bm1)@Wm2^T+bm2); Y1 in LDS
__device__ void mlp_phase(float* __restrict__ ws, char* smem, int rb)
{
    ushort_t* y1 = (ushort_t*)smem;            // [16*1024] bf16 swz
    ushort_t* at = (ushort_t*)(smem + 32768);  // [16*256] bf16 swz
    const int tid = threadIdx.x;
    const float* HL = ws + OFF_HL; const float* PHP = ws + OFF_PHP; float* HC = ws + OFF_HC;

    for (int idx = tid; idx < 512; idx += 256) {
        const int r = idx >> 5, k8 = idx & 31, k = k8*8, gr = rb + r;
        const float* src = (k < 128) ? (HL + gr*128 + k) : (PHP + gr*128 + (k - 128));
        float4 f0 = ((const float4*)src)[0];
        float4 f1 = ((const float4*)src)[1];
        uint4 val;
        val.x = f2b(f0.x) | (f2b(f0.y) << 16);
        val.y = f2b(f0.z) | (f2b(f0.w) << 16);
        val.z = f2b(f1.x) | (f2b(f1.y) << 16);
        val.w = f2b(f1.z) | (f2b(f1.w) << 16);
        *(uint4*)&at[(r*256 + k) ^ ((r & 7) << 3)] = val;
    }
    __syncthreads();

    const int lane = tid & 63, w = tid >> 6;
    const int arow = lane & 15, kch = (lane >> 4) * 8;
    const ushort_t* M1F = (const ushort_t*)(ws + OFF_M1F);
    const ushort_t* M2F = (const ushort_t*)(ws + OFF_M2F);

    short8v af[8];
    #pragma unroll
    for (int kk = 0; kk < 8; kk++)
        af[kk] = *(const short8v*)&at[(arow*256 + kk*32 + kch) ^ ((arow & 7) << 3)];

    #pragma unroll 2
    for (int ct = 0; ct < 16; ct++) {
        const int ntg = w*16 + ct;
        f32x4 acc = (f32x4){0.f,0.f,0.f,0.f};
        #pragma unroll
        for (int kk = 0; kk < 8; kk++) {
            short8v b = *(const short8v*)&M1F[((ntg*8 + kk)*64 + lane)*8];
            acc = __builtin_amdgcn_mfma_f32_16x16x32_bf16(af[kk], b, acc, 0, 0, 0);
        }
        const int col = ntg*16 + (lane & 15);
        const float bb = ws[F_BM1 + col];
        const int rb4 = (lane >> 4) << 2;
        #pragma unroll
        for (int reg = 0; reg < 4; reg++) {
            const int rloc = rb4 + reg;
            const float v = fmaxf(acc[reg] + bb, 0.f);
            y1[(rloc*1024 + col) ^ ((rloc & 7) << 3)] = (ushort_t)f2b(v);
        }
    }
    __syncthreads();

    f32x4 acc2[2];
    acc2[0] = (f32x4){0.f,0.f,0.f,0.f};
    acc2[1] = (f32x4){0.f,0.f,0.f,0.f};
    #pragma unroll 4
    for (int kk = 0; kk < 32; kk++) {
        short8v a = *(const short8v*)&y1[(arow*1024 + kk*32 + kch) ^ ((arow & 7) << 3)];
        #pragma unroll
        for (int ct = 0; ct < 2; ct++) {
            const int ntg = w*2 + ct;
            short8v b = *(const short8v*)&M2F[((ntg*32 + kk)*64 + lane)*8];
            acc2[ct] = __builtin_amdgcn_mfma_f32_16x16x32_bf16(a, b, acc2[ct], 0, 0, 0);
        }
    }
    #pragma unroll
    for (int ct = 0; ct < 2; ct++) {
        const int ntg = w*2 + ct;
        const int col = ntg*16 + (lane & 15);
        const float bb = ws[F_BM2 + col];
        const int rb4 = (lane >> 4) << 2;
        #pragma unroll
        for (int reg = 0; reg < 4; reg++)
            HC[(rb + rb4 + reg)*128 + col] = fmaxf(acc2[ct][reg] + bb, 0.f);
    }
    __syncthreads();
}

// ---------------- the persistent whole-T-loop kernel ----------------
// Deps: lstm->pool (HP,LP cross-block) BAR; pool->mlp (PHP cross-block) BAR;
// mlp->next lstm is BLOCK-LOCAL (block b owns rows 16b..16b+15 in both) - no barrier.
__global__ __launch_bounds__(256, 1) void k_run(float* __restrict__ ws, float* __restrict__ out)
{
    __shared__ __align__(16) char smem[45184];
    const int bid = blockIdx.x;
    uint_t* bar = (uint_t*)(ws + OFF_BAR);

    for (int t = 0; t < T_; t++) {
        if (bid < 64) lstm_phase(ws, out, smem, bid*16, t, (t < T_-1) ? 1 : 0);
        if (t == T_-1) break;
        grid_barrier(bar);
        pool_phase(ws, smem, bid);
        grid_barrier(bar);
        if (bid < 64) mlp_phase(ws, smem, bid*16);
    }
}

extern "C" void kernel_launch(void* const* d_in, const int* in_sizes, int n_in,
                              void* d_out, int out_size, void* d_ws, size_t ws_size,
                              hipStream_t stream) {
    float* ws = (float*)d_ws;
    float* out = (float*)d_out;   // reference output dtype is float32

    Ptrs ptrs;   // 22 float tensors, skipping seq_start_end (d_in[4]) and seq_len (d_in[5])
    for (int t = 0; t < 22; t++) ptrs.p[t] = d_in[t < 4 ? t : t + 2];

    k_conv <<<3614, 256, 0, stream>>>(ptrs, ws);   // ceil(925058/256)
    k_init <<<1024, 128, 0, stream>>>(ws);
    k_pre2 <<<2,    256, 0, stream>>>(ws);
    k_packs<<<2432, 256, 0, stream>>>(ws);
    k_run  <<<256,  256, 0, stream>>>(ws, out);
}

// Round 10
// 1071.462 us; speedup vs baseline: 4.7691x; 4.7691x over previous
//
#include <hip/hip_runtime.h>
#include <hip/hip_bf16.h>
#include <math.h>

typedef unsigned short ushort_t;
typedef unsigned int uint_t;

// Problem constants: S=32 scenes, N=32 peds, B=1024, E=64, H=128, PRE=512, MLP_D=1024, T=12
// All float inputs are f32; output is f32.
#define T_ 12

// ---- ws layout (float offsets) ----
#define F_LP0   0         // last_pos      (2048)
#define F_LPR   2048      // last_pos_rel  (2048)
#define F_H0    4096      // h0            (131072)
#define F_C0    135168    // c0            (131072)
#define F_WSP   266240    // Wsp (64,2)
#define F_BSP   266368    // bsp (64)
#define F_WIH   266432    // Wih (512,64)
#define F_WHH   299200    // Whh (512,128)
#define F_BIH   364736
#define F_BHH   365248
#define F_WH2P  365760    // (2,128)
#define F_BH2P  366016    // (2)
#define F_WPE   366032    // (64,2)
#define F_BPE   366160    // (64)
#define F_WP1   366224    // (512,192)
#define F_BP1   464528    // (512)
#define F_WP2   465040    // (128,512)
#define F_BP2   530576    // (128)
#define F_WM1   530704    // (1024,256)
#define F_BM1   792848    // (1024)
#define F_WM2   793872    // (128,1024)
#define F_BM2   924944    // (128)
// State / derived:
#define OFF_HC   925072   // carry hidden (B,128)
#define OFF_HL   1056144  // lstm hidden  (B,128)
#define OFF_C    1187216  // cell         (B,128)
#define OFF_X    1318288  // lstm input   (B,64)
#define OFF_LP   1383824  // positions    (B,2)
#define OFF_HP   1385872  // hp f32 (B,512)
#define OFF_A2   1910160  // (2,512)
#define OFF_B512 1911184  // (512)
#define OFF_W2F  1911696  // Wp2 bf16 B-frag pack (65536 ushorts)
#define OFF_PHP  1977232  // pool max output (B,128)
#define OFF_HPF  2108304  // Wp1b B-frag pack (65536 ushorts)
#define OFF_M1F  2141072  // Wm1 B-frag pack (262144 ushorts)
#define OFF_M2F  2272144  // Wm2 B-frag pack (131072 ushorts)
#define OFF_BG   2337680  // gate bias bih+bhh (512)
#define OFF_LF   2338192  // Wih|Whh B-frag pack (98304 ushorts = 49152 floats)
#define OFF_BAR  2387344  // arrival counter (own cacheline)
#define OFF_GEN  2387408  // generation word (separate cacheline, +256B)
// total ~2387472 floats = ~9.55 MB of d_ws

typedef __attribute__((ext_vector_type(8))) short short8v;   // 8 bf16 (4 VGPRs)
typedef __attribute__((ext_vector_type(4))) float f32x4;

__device__ __forceinline__ float sigf(float x){ return 1.0f/(1.0f+expf(-x)); }
__device__ __forceinline__ uint_t f2b(float f){  // RNE f32->bf16 (bits in low 16)
    uint_t u = __float_as_uint(f);
    return (u + 0x7FFFu + ((u >> 16) & 1u)) >> 16;
}

struct Ptrs { const void* p[22]; };

// ---- grid barrier: count & generation on SEPARATE cachelines; relaxed polling with
// one acquire at exit; release via store (not RMW). Co-residency by construction:
// 256 blocks, 45KB LDS, launch_bounds(256,1) -> 1 block/CU on 256 CUs.
__device__ __forceinline__ void grid_barrier(uint_t* cnt, uint_t* gen)
{
    __syncthreads();
    if (threadIdx.x == 0) {
        uint_t g = __hip_atomic_load(gen, __ATOMIC_RELAXED, __HIP_MEMORY_SCOPE_AGENT);
        if (__hip_atomic_fetch_add(cnt, 1u, __ATOMIC_ACQ_REL, __HIP_MEMORY_SCOPE_AGENT) == 255u) {
            __hip_atomic_store(cnt, 0u, __ATOMIC_RELAXED, __HIP_MEMORY_SCOPE_AGENT);
            __hip_atomic_store(gen, g + 1u, __ATOMIC_RELEASE, __HIP_MEMORY_SCOPE_AGENT);
        } else {
            while (__hip_atomic_load(gen, __ATOMIC_RELAXED, __HIP_MEMORY_SCOPE_AGENT) == g)
                __builtin_amdgcn_s_sleep(8);
            (void)__hip_atomic_load(gen, __ATOMIC_ACQUIRE, __HIP_MEMORY_SCOPE_AGENT);
        }
    }
    __syncthreads();
}

// ---------------- copy all f32 inputs into consolidated ws region ----------------
__global__ __launch_bounds__(256) void k_conv(Ptrs ptrs, float* __restrict__ ws)
{
    const int cums[22] = {0,2048,4096,135168,266240,266368,266432,299200,364736,
                          365248,365760,366016,366018,366146,366210,464514,465026,
                          530562,530690,792834,793858,924930};
    const int dof[22]  = {F_LP0,F_LPR,F_H0,F_C0,F_WSP,F_BSP,F_WIH,F_WHH,F_BIH,F_BHH,
                          F_WH2P,F_BH2P,F_WPE,F_BPE,F_WP1,F_BP1,F_WP2,F_BP2,F_WM1,
                          F_BM1,F_WM2,F_BM2};
    const int TOTAL = 925058;
    int g = blockIdx.x*256 + threadIdx.x;
    if (g < TOTAL) {
        int t = 0;
        #pragma unroll
        for (int i = 1; i < 22; i++) t += (g >= cums[i]);
        int li = g - cums[t];
        ws[dof[t] + li] = ((const float*)ptrs.p[t])[li];
    }
}

// ---------------- init: h,c copy; x0 = lpr@Wsp^T+bsp; lp = last_pos; barrier reset ----------------
__global__ __launch_bounds__(128) void k_init(float* __restrict__ ws)
{
    const int b = blockIdx.x, tid = threadIdx.x;
    ws[OFF_HC + b*128 + tid] = ws[F_H0 + b*128 + tid];
    ws[OFF_C  + b*128 + tid] = ws[F_C0 + b*128 + tid];
    if (tid < 64) {
        float p0 = ws[F_LPR + b*2], p1 = ws[F_LPR + b*2 + 1];
        ws[OFF_X + b*64 + tid] = p0*ws[F_WSP + tid*2] + p1*ws[F_WSP + tid*2+1] + ws[F_BSP + tid];
    }
    if (tid < 2) ws[OFF_LP + b*2 + tid] = ws[F_LP0 + b*2 + tid];
    if (b == 0 && tid == 0) {
        ((uint_t*)(ws + OFF_BAR))[0] = 0u;   // re-zero barrier state each call
        ((uint_t*)(ws + OFF_GEN))[0] = 0u;
    }
}

// ---------------- A2/B512 + gate bias ----------------
__global__ __launch_bounds__(256) void k_pre2(float* __restrict__ ws)
{
    const int k = blockIdx.x*256 + threadIdx.x;   // 0..511
    float a0 = 0.f, a1 = 0.f, bb = 0.f;
    for (int e = 0; e < 64; e++) {
        float w = ws[F_WP1 + k*192 + e];
        a0 += ws[F_WPE + e*2 + 0] * w;
        a1 += ws[F_WPE + e*2 + 1] * w;
        bb += ws[F_BPE + e]       * w;
    }
    ws[OFF_A2 + k]       = a0;
    ws[OFF_A2 + 512 + k] = a1;
    ws[OFF_B512 + k]     = bb + ws[F_BP1 + k];
    ws[OFF_BG + k]       = ws[F_BIH + k] + ws[F_BHH + k];
}

// ---------------- merged B-frag packs: W2F, HPF, M1F, M2F, LF ----------------
__global__ __launch_bounds__(256) void k_packs(float* __restrict__ ws)
{
    const int g = blockIdx.x*256 + threadIdx.x;
    if (g >= 622592) return;
    const int cums[6] = {0,65536,131072,393216,524288,622592};
    int rgn = 0;
    #pragma unroll
    for (int i = 1; i < 5; i++) rgn += (g >= cums[i]);
    const int li = g - cums[rgn];
    const int Ks[5]   = {512, 128, 256, 1024, 192};
    const int src[5]  = {F_WP2, F_WP1, F_WM1, F_WM2, 0};
    const int strd[5] = {512, 192, 256, 1024, 0};
    const int coff[5] = {0, 64, 0, 0, 0};
    const int dst[5]  = {OFF_W2F, OFF_HPF, OFF_M1F, OFF_M2F, OFF_LF};
    const int K = Ks[rgn];
    const int i = li & 7, lane = (li >> 3) & 63, rest = li >> 9;
    const int nkk = K >> 5, kk = rest % nkk, nt = rest / nkk;
    const int n = nt*16 + (lane & 15);
    const int k = kk*32 + ((lane >> 4) << 3) + i;
    float v;
    if (rgn == 4) v = (k < 64) ? ws[F_WIH + n*64 + k] : ws[F_WHH + n*128 + (k - 64)];
    else          v = ws[src[rgn] + n*strd[rgn] + coff[rgn] + k];
    ((ushort_t*)(ws + dst[rgn]))[li] = (ushort_t)f2b(v);
}

// ================= persistent-kernel phase functions =================

// LSTM 16 rows: gates MFMA + pointwise + h2p + X refresh + hp GEMM
__device__ void lstm_phase(float* __restrict__ ws, float* __restrict__ out,
                           char* smem, int rb, int tstep, int do_hp)
{
    ushort_t* atile = (ushort_t*)smem;              // [16*192] bf16 swz (stage)
    float*    gates = (float*)smem;                 // [16][512] f32
    float*    h2s   = (float*)(smem + 32768);       // [16][128] f32
    ushort_t* h2b   = (ushort_t*)(smem + 40960);    // [16*128] bf16 swz
    float*    relsh = (float*)(smem + 45056);       // [16][2]
    const int tid = threadIdx.x;
    float* X  = ws + OFF_X;  float* HC = ws + OFF_HC; float* C = ws + OFF_C;
    float* HL = ws + OFF_HL; float* LP = ws + OFF_LP;

    // stage A = [X(64) | HC(128)]
    for (int idx = tid; idx < 384; idx += 256) {
        const int r = idx / 24, k8 = idx - r*24, k = k8*8, gr = rb + r;
        const float* src = (k < 64) ? (X + gr*64 + k) : (HC + gr*128 + (k - 64));
        float4 f0 = ((const float4*)src)[0];
        float4 f1 = ((const float4*)src)[1];
        uint4 val;
        val.x = f2b(f0.x) | (f2b(f0.y) << 16);
        val.y = f2b(f0.z) | (f2b(f0.w) << 16);
        val.z = f2b(f1.x) | (f2b(f1.y) << 16);
        val.w = f2b(f1.z) | (f2b(f1.w) << 16);
        *(uint4*)&atile[(r*192 + k) ^ ((r & 7) << 3)] = val;
    }
    __syncthreads();

    const int lane = tid & 63, w = tid >> 6;
    const int arow = lane & 15, kch = (lane >> 4) * 8;

    short8v afr[6];
    #pragma unroll
    for (int kk = 0; kk < 6; kk++)
        afr[kk] = *(const short8v*)&atile[(arow*192 + kk*32 + kch) ^ ((arow & 7) << 3)];
    __syncthreads();   // atile free -> gates region

    const ushort_t* LF = (const ushort_t*)(ws + OFF_LF);
    #pragma unroll
    for (int ct = 0; ct < 8; ct++) {
        const int ntg = w*8 + ct;
        f32x4 acc = (f32x4){0.f,0.f,0.f,0.f};
        #pragma unroll
        for (int kk = 0; kk < 6; kk++) {
            short8v b = *(const short8v*)&LF[((ntg*6 + kk)*64 + lane)*8];
            acc = __builtin_amdgcn_mfma_f32_16x16x32_bf16(afr[kk], b, acc, 0, 0, 0);
        }
        const int col = ntg*16 + (lane & 15);
        const float bb = ws[OFF_BG + col];
        const int rb4 = (lane >> 4) << 2;
        #pragma unroll
        for (int reg = 0; reg < 4; reg++)
            gates[(rb4 + reg)*512 + col] = acc[reg] + bb;
    }
    __syncthreads();

    // pointwise
    const int hcol = tid & 127, half = tid >> 7;
    float h2v[8];
    #pragma unroll 2
    for (int rr = 0; rr < 8; rr++) {
        const int r = half*8 + rr, gr = rb + r;
        float gi = gates[r*512 + hcol];
        float gf = gates[r*512 + 128 + hcol];
        float gg = gates[r*512 + 256 + hcol];
        float go = gates[r*512 + 384 + hcol];
        float c2 = sigf(gf) * C[gr*128 + hcol] + sigf(gi) * tanhf(gg);
        float h2 = sigf(go) * tanhf(c2);
        C [gr*128 + hcol] = c2;
        HL[gr*128 + hcol] = h2;
        h2v[rr] = h2;
    }
    __syncthreads();
    #pragma unroll
    for (int rr = 0; rr < 8; rr++) {
        const int r = half*8 + rr;
        h2s[r*128 + hcol] = h2v[rr];
        h2b[(r*128 + hcol) ^ ((r & 7) << 3)] = (ushort_t)f2b(h2v[rr]);
    }
    __syncthreads();

    // h2p: rel = h2 @ Wh2p^T + bh2p  (32 dots, 8 lanes each)
    {
        const int grp = tid >> 3, sub = tid & 7;
        const int r = grp >> 1, rr = grp & 1;
        float a = 0.f;
        #pragma unroll 4
        for (int l = 0; l < 16; l++) {
            const int k = sub*16 + l;
            a += h2s[r*128 + k] * ws[F_WH2P + rr*128 + k];
        }
        a += __shfl_xor(a, 1, 64);
        a += __shfl_xor(a, 2, 64);
        a += __shfl_xor(a, 4, 64);
        if (sub == 0) {
            const float rel = a + ws[F_BH2P + rr];
            const int gr = rb + r;
            out[tstep*2048 + gr*2 + rr] = rel;
            LP[gr*2 + rr] += rel;
            relsh[r*2 + rr] = rel;
        }
    }
    __syncthreads();

    // X refresh
    {
        const int col = tid & 63, rq = tid >> 6;
        const float w0 = ws[F_WSP + col*2], w1 = ws[F_WSP + col*2 + 1], bs = ws[F_BSP + col];
        #pragma unroll
        for (int rr = 0; rr < 4; rr++) {
            const int r = rq*4 + rr;
            X[(rb + r)*64 + col] = relsh[r*2]*w0 + relsh[r*2 + 1]*w1 + bs;
        }
    }

    // hp GEMM: HP = h2 @ Wp1b^T + B512
    if (do_hp) {
        const ushort_t* HPF = (const ushort_t*)(ws + OFF_HPF);
        float* HP = ws + OFF_HP;
        short8v hf[4];
        #pragma unroll
        for (int kk = 0; kk < 4; kk++)
            hf[kk] = *(const short8v*)&h2b[(arow*128 + kk*32 + kch) ^ ((arow & 7) << 3)];
        #pragma unroll
        for (int ct = 0; ct < 8; ct++) {
            const int ntg = w*8 + ct;
            f32x4 acc = (f32x4){0.f,0.f,0.f,0.f};
            #pragma unroll
            for (int kk = 0; kk < 4; kk++) {
                short8v b = *(const short8v*)&HPF[((ntg*4 + kk)*64 + lane)*8];
                acc = __builtin_amdgcn_mfma_f32_16x16x32_bf16(hf[kk], b, acc, 0, 0, 0);
            }
            const int col = ntg*16 + (lane & 15);
            const float bb = ws[OFF_B512 + col];
            const int rb4 = (lane >> 4) << 2;
            #pragma unroll
            for (int reg = 0; reg < 4; reg++)
                HP[(rb + rb4 + reg)*512 + col] = acc[reg] + bb;
        }
    }
}

// Pool: 4 sequential (scene,i) per block
__device__ void pool_phase(float* __restrict__ ws, char* smem, int bid)
{
    uint_t* a1b = (uint_t*)smem;   // 32 KB: bf16 [j][k] swz
    const int tid = threadIdx.x;
    const int s  = bid >> 3;
    const int ig = (bid & 7) * 4;
    const float* LP = ws + OFF_LP;
    const float4* HP4 = (const float4*)(ws + OFF_HP);
    const float4* A2q = (const float4*)(ws + OFF_A2);
    const ushort_t* w2f = (const ushort_t*)(ws + OFF_W2F);
    const ushort_t* a1u = (const ushort_t*)a1b;
    const int lane = tid & 63, w = tid >> 6;
    const int r0row = (lane & 15), kchunk = (lane >> 4) * 8;

    for (int q = 0; q < 4; q++) {
        const int si = s*32 + ig + q;
        const float c0 = LP[si*2], c1 = LP[si*2 + 1];

        for (int idx = tid; idx < 32*128; idx += 256) {
            const int jl = idx >> 7, k4 = idx & 127;
            const int gj = s*32 + jl;
            const float r0 = LP[gj*2] - c0, r1 = LP[gj*2+1] - c1;
            float4 hp = HP4[gj*128 + k4];
            float4 a0 = A2q[k4];
            float4 a1v = A2q[128 + k4];
            float x = fmaxf(hp.x + r0*a0.x + r1*a1v.x, 0.f);
            float y = fmaxf(hp.y + r0*a0.y + r1*a1v.y, 0.f);
            float z = fmaxf(hp.z + r0*a0.z + r1*a1v.z, 0.f);
            float w2 = fmaxf(hp.w + r0*a0.w + r1*a1v.w, 0.f);
            const int u = (jl*512 + k4*4) ^ ((jl & 7) << 3);
            uint2 pk;
            pk.x = f2b(x) | (f2b(y) << 16);
            pk.y = f2b(z) | (f2b(w2) << 16);
            *(uint2*)&a1b[u >> 1] = pk;
        }
        __syncthreads();

        f32x4 acc[2][2];
        #pragma unroll
        for (int jt = 0; jt < 2; jt++)
            #pragma unroll
            for (int t = 0; t < 2; t++) acc[jt][t] = (f32x4){0.f,0.f,0.f,0.f};

        #pragma unroll 4
        for (int kk = 0; kk < 16; kk++) {
            const int kbase = kk*32 + kchunk;
            const int ra = r0row, rb2 = 16 + r0row;
            short8v a0 = *(const short8v*)&a1u[(ra *512 + kbase) ^ ((ra  & 7) << 3)];
            short8v a1f= *(const short8v*)&a1u[(rb2*512 + kbase) ^ ((rb2 & 7) << 3)];
            #pragma unroll
            for (int t = 0; t < 2; t++) {
                const int mt = 2*w + t;
                short8v b = *(const short8v*)&w2f[((mt*16 + kk)*64 + lane)*8];
                acc[0][t] = __builtin_amdgcn_mfma_f32_16x16x32_bf16(a0,  b, acc[0][t], 0, 0, 0);
                acc[1][t] = __builtin_amdgcn_mfma_f32_16x16x32_bf16(a1f, b, acc[1][t], 0, 0, 0);
            }
        }

        float vt[2];
        #pragma unroll
        for (int t = 0; t < 2; t++) {
            float m0 = fmaxf(fmaxf(acc[0][t][0], acc[0][t][1]), fmaxf(acc[0][t][2], acc[0][t][3]));
            float m1 = fmaxf(fmaxf(acc[1][t][0], acc[1][t][1]), fmaxf(acc[1][t][2], acc[1][t][3]));
            float m = fmaxf(m0, m1);
            m = fmaxf(m, __shfl_xor(m, 16, 64));
            m = fmaxf(m, __shfl_xor(m, 32, 64));
            const int col = (2*w + t)*16 + (lane & 15);
            vt[t] = fmaxf(m + ws[F_BP2 + col], 0.f);
        }
        if (lane < 32) {
            const int tl = lane >> 4;
            const int col = (2*w + tl)*16 + (lane & 15);
            ws[OFF_PHP + si*128 + col] = tl ? vt[1] : vt[0];
        }
        __syncthreads();
    }
}

// Fused MLP 16 rows: HC = relu(relu([HL|PHP]@Wm1^T+bm1)@Wm2^T+bm2); Y1 in LDS
__device__ void mlp_phase(float* __restrict__ ws, char* smem, int rb)
{
    ushort_t* y1 = (ushort_t*)smem;            // [16*1024] bf16 swz
    ushort_t* at = (ushort_t*)(smem + 32768);  // [16*256] bf16 swz
    const int tid = threadIdx.x;
    const float* HL = ws + OFF_HL; const float* PHP = ws + OFF_PHP; float* HC = ws + OFF_HC;

    for (int idx = tid; idx < 512; idx += 256) {
        const int r = idx >> 5, k8 = idx & 31, k = k8*8, gr = rb + r;
        const float* src = (k < 128) ? (HL + gr*128 + k) : (PHP + gr*128 + (k - 128));
        float4 f0 = ((const float4*)src)[0];
        float4 f1 = ((const float4*)src)[1];
        uint4 val;
        val.x = f2b(f0.x) | (f2b(f0.y) << 16);
        val.y = f2b(f0.z) | (f2b(f0.w) << 16);
        val.z = f2b(f1.x) | (f2b(f1.y) << 16);
        val.w = f2b(f1.z) | (f2b(f1.w) << 16);
        *(uint4*)&at[(r*256 + k) ^ ((r & 7) << 3)] = val;
    }
    __syncthreads();

    const int lane = tid & 63, w = tid >> 6;
    const int arow = lane & 15, kch = (lane >> 4) * 8;
    const ushort_t* M1F = (const ushort_t*)(ws + OFF_M1F);
    const ushort_t* M2F = (const ushort_t*)(ws + OFF_M2F);

    short8v af[8];
    #pragma unroll
    for (int kk = 0; kk < 8; kk++)
        af[kk] = *(const short8v*)&at[(arow*256 + kk*32 + kch) ^ ((arow & 7) << 3)];

    #pragma unroll 2
    for (int ct = 0; ct < 16; ct++) {
        const int ntg = w*16 + ct;
        f32x4 acc = (f32x4){0.f,0.f,0.f,0.f};
        #pragma unroll
        for (int kk = 0; kk < 8; kk++) {
            short8v b = *(const short8v*)&M1F[((ntg*8 + kk)*64 + lane)*8];
            acc = __builtin_amdgcn_mfma_f32_16x16x32_bf16(af[kk], b, acc, 0, 0, 0);
        }
        const int col = ntg*16 + (lane & 15);
        const float bb = ws[F_BM1 + col];
        const int rb4 = (lane >> 4) << 2;
        #pragma unroll
        for (int reg = 0; reg < 4; reg++) {
            const int rloc = rb4 + reg;
            const float v = fmaxf(acc[reg] + bb, 0.f);
            y1[(rloc*1024 + col) ^ ((rloc & 7) << 3)] = (ushort_t)f2b(v);
        }
    }
    __syncthreads();

    f32x4 acc2[2];
    acc2[0] = (f32x4){0.f,0.f,0.f,0.f};
    acc2[1] = (f32x4){0.f,0.f,0.f,0.f};
    #pragma unroll 4
    for (int kk = 0; kk < 32; kk++) {
        short8v a = *(const short8v*)&y1[(arow*1024 + kk*32 + kch) ^ ((arow & 7) << 3)];
        #pragma unroll
        for (int ct = 0; ct < 2; ct++) {
            const int ntg = w*2 + ct;
            short8v b = *(const short8v*)&M2F[((ntg*32 + kk)*64 + lane)*8];
            acc2[ct] = __builtin_amdgcn_mfma_f32_16x16x32_bf16(a, b, acc2[ct], 0, 0, 0);
        }
    }
    #pragma unroll
    for (int ct = 0; ct < 2; ct++) {
        const int ntg = w*2 + ct;
        const int col = ntg*16 + (lane & 15);
        const float bb = ws[F_BM2 + col];
        const int rb4 = (lane >> 4) << 2;
        #pragma unroll
        for (int reg = 0; reg < 4; reg++)
            HC[(rb + rb4 + reg)*128 + col] = fmaxf(acc2[ct][reg] + bb, 0.f);
    }
    __syncthreads();
}

// ---------------- the persistent whole-T-loop kernel ----------------
// Deps: lstm->pool (HP,LP cross-block) BAR; pool->mlp (PHP cross-block) BAR;
// mlp->next lstm is BLOCK-LOCAL (block b owns rows 16b..16b+15 in both) - no barrier.
__global__ __launch_bounds__(256, 1) void k_run(float* __restrict__ ws, float* __restrict__ out)
{
    __shared__ __align__(16) char smem[45184];
    const int bid = blockIdx.x;
    uint_t* cnt = (uint_t*)(ws + OFF_BAR);
    uint_t* gen = (uint_t*)(ws + OFF_GEN);

    for (int t = 0; t < T_; t++) {
        if (bid < 64) lstm_phase(ws, out, smem, bid*16, t, (t < T_-1) ? 1 : 0);
        if (t == T_-1) break;
        grid_barrier(cnt, gen);
        pool_phase(ws, smem, bid);
        grid_barrier(cnt, gen);
        if (bid < 64) mlp_phase(ws, smem, bid*16);
    }
}

extern "C" void kernel_launch(void* const* d_in, const int* in_sizes, int n_in,
                              void* d_out, int out_size, void* d_ws, size_t ws_size,
                              hipStream_t stream) {
    float* ws = (float*)d_ws;
    float* out = (float*)d_out;   // reference output dtype is float32

    Ptrs ptrs;   // 22 float tensors, skipping seq_start_end (d_in[4]) and seq_len (d_in[5])
    for (int t = 0; t < 22; t++) ptrs.p[t] = d_in[t < 4 ? t : t + 2];

    k_conv <<<3614, 256, 0, stream>>>(ptrs, ws);   // ceil(925058/256)
    k_init <<<1024, 128, 0, stream>>>(ws);
    k_pre2 <<<2,    256, 0, stream>>>(ws);
    k_packs<<<2432, 256, 0, stream>>>(ws);
    k_run  <<<256,  256, 0, stream>>>(ws, out);
}